// Round 1
// baseline (303.368 us; speedup 1.0000x reference)
//
#include <hip/hip_runtime.h>

// ---------------------------------------------------------------------------
// GNNBase: B=512, N=32, F=16, H=128, E=16, NE=3, L=2, D0=32
// Pipeline:
//   k_prep : transpose lin1_w / linh_w[0,1] / fc2a_w -> bf16 W^T in ws
//   k_pair : per (b, 4 c's) block: 128-pair tile, 3 MFMA layers
//            (bias+relu+LN fused in C-fragment registers), masked reduce -> h
//   k_score: s[row] = relu(h@fc2a+b)@fc2b + b2 for all 16384 rows (MFMA)
//   k_stats: global softmax max & sum-of-exp over 16384 scores
//   k_final: 512 agent rows only: v=LN(relu(h@fc3)), x=LN(relu(alpha*v@fc4))
// ---------------------------------------------------------------------------

typedef __attribute__((ext_vector_type(8))) __bf16 bf16x8;
typedef __attribute__((ext_vector_type(4))) float  f32x4;

__device__ __forceinline__ unsigned short f2bf(float f) {
  union { float f; unsigned u; } v; v.f = f;
  unsigned u = v.u;
  u += 0x7FFFu + ((u >> 16) & 1u);   // RTNE
  return (unsigned short)(u >> 16);
}

__device__ __forceinline__ bf16x8 lds_frag(const unsigned short* p) {
  union { uint4 u; bf16x8 v; } x;
  x.u = *(const uint4*)p;            // ds_read_b128
  return x.v;
}

__device__ __forceinline__ f32x4 mfma16(bf16x8 a, bf16x8 b, f32x4 c) {
  return __builtin_amdgcn_mfma_f32_16x16x32_bf16(a, b, c, 0, 0, 0);
}

// ---------------------------------------------------------------------------
// k_prep: W^T bf16 tables. WT0:[128n][32k]  WT1/WT2/WT3:[128n][128k]
// ---------------------------------------------------------------------------
__global__ void k_prep(const float* __restrict__ lin1_w, const float* __restrict__ linh_w,
                       const float* __restrict__ fc2a_w,
                       unsigned short* __restrict__ WT0, unsigned short* __restrict__ WT1,
                       unsigned short* __restrict__ WT2, unsigned short* __restrict__ WT3) {
  int idx = blockIdx.x * 256 + threadIdx.x;
  if (idx < 128 * 32) {
    int n = idx >> 5, k = idx & 31;
    WT0[idx] = f2bf(lin1_w[k * 128 + n]);
  }
  if (idx < 128 * 128) {
    int n = idx >> 7, k = idx & 127;
    WT1[idx] = f2bf(linh_w[k * 128 + n]);
    WT2[idx] = f2bf(linh_w[16384 + k * 128 + n]);
    WT3[idx] = f2bf(fc2a_w[k * 128 + n]);
  }
}

// ---------------------------------------------------------------------------
// k_pair epilogues. C-fragment layout (16x16x32): col = tj*16 + (lane&15),
// row = 32*wave + ti*16 + quad*4 + reg.  LN row-stats via shfl_xor 1/2/4/8.
// ---------------------------------------------------------------------------
__device__ __forceinline__ void epilogue_store(f32x4 (&acc)[2][8], const float* P, int pbase,
                                               unsigned short* Xs, int wv, int li, int quad) {
  float bs[8], g[8], be[8];
#pragma unroll
  for (int tj = 0; tj < 8; ++tj) {
    int col = tj * 16 + li;
    bs[tj] = P[pbase + col];
    g[tj]  = P[pbase + 128 + col];
    be[tj] = P[pbase + 256 + col];
  }
#pragma unroll
  for (int ti = 0; ti < 2; ++ti) {
#pragma unroll
    for (int rg = 0; rg < 4; ++rg) {
      float v[8], s1 = 0.f, s2 = 0.f;
#pragma unroll
      for (int tj = 0; tj < 8; ++tj) {
        float x = acc[ti][tj][rg] + bs[tj];
        x = fmaxf(x, 0.f);
        v[tj] = x; s1 += x; s2 += x * x;
      }
#pragma unroll
      for (int m = 1; m < 16; m <<= 1) { s1 += __shfl_xor(s1, m); s2 += __shfl_xor(s2, m); }
      float mean = s1 * 0.0078125f;
      float var  = s2 * 0.0078125f - mean * mean;
      float inv  = rsqrtf(var + 1e-5f);
      int row = 32 * wv + ti * 16 + quad * 4 + rg;
#pragma unroll
      for (int tj = 0; tj < 8; ++tj) {
        float o = (v[tj] - mean) * inv * g[tj] + be[tj];
        Xs[row * 136 + tj * 16 + li] = f2bf(o);
      }
    }
  }
}

__device__ __forceinline__ void epilogue_agg(f32x4 (&acc)[2][8], const float* P, int pbase,
                                             const float* mArr, float* hrow,
                                             int wv, int li, int quad) {
  float bs[8], g[8], be[8], cs[8];
#pragma unroll
  for (int tj = 0; tj < 8; ++tj) {
    int col = tj * 16 + li;
    bs[tj] = P[pbase + col];
    g[tj]  = P[pbase + 128 + col];
    be[tj] = P[pbase + 256 + col];
    cs[tj] = 0.f;
  }
#pragma unroll
  for (int ti = 0; ti < 2; ++ti) {
#pragma unroll
    for (int rg = 0; rg < 4; ++rg) {
      float v[8], s1 = 0.f, s2 = 0.f;
#pragma unroll
      for (int tj = 0; tj < 8; ++tj) {
        float x = acc[ti][tj][rg] + bs[tj];
        x = fmaxf(x, 0.f);
        v[tj] = x; s1 += x; s2 += x * x;
      }
#pragma unroll
      for (int m = 1; m < 16; m <<= 1) { s1 += __shfl_xor(s1, m); s2 += __shfl_xor(s2, m); }
      float mean = s1 * 0.0078125f;
      float var  = s2 * 0.0078125f - mean * mean;
      float inv  = rsqrtf(var + 1e-5f);
      int row = 32 * wv + ti * 16 + quad * 4 + rg;
      float mk = mArr[row];
#pragma unroll
      for (int tj = 0; tj < 8; ++tj)
        cs[tj] += mk * ((v[tj] - mean) * inv * g[tj] + be[tj]);
    }
  }
#pragma unroll
  for (int tj = 0; tj < 8; ++tj) {
    cs[tj] += __shfl_xor(cs[tj], 16);
    cs[tj] += __shfl_xor(cs[tj], 32);
  }
  if (quad == 0) {
#pragma unroll
    for (int tj = 0; tj < 8; ++tj) hrow[tj * 16 + li] = cs[tj];
  }
}

// ---------------------------------------------------------------------------
// k_pair: block = (b, c0..c0+3). wave w owns c = c0+w (rows p = 32w + r).
// LDS: Xs 128x136 bf16 (overlaid by As 128x40 for layer 0), Ws 128x136 bf16,
//      mask[128] f32, params 9x128 f32.  Total 74752 B -> 2 blocks/CU.
// ---------------------------------------------------------------------------
#define SM_X 0
#define SM_W 34816
#define SM_M 69632
#define SM_P 70144
#define SM_TOTAL 74752

__global__ __launch_bounds__(256, 2)
void k_pair(const float* __restrict__ node_obs, const float* __restrict__ adj,
            const float* __restrict__ ent_emb,
            const float* __restrict__ lin1_b, const float* __restrict__ ln1_g,
            const float* __restrict__ ln1_beta,
            const float* __restrict__ linh_b, const float* __restrict__ lnh_g,
            const float* __restrict__ lnh_b,
            const unsigned short* __restrict__ WT0, const unsigned short* __restrict__ WT1,
            const unsigned short* __restrict__ WT2,
            float* __restrict__ hout) {
  __shared__ alignas(16) char smem[SM_TOTAL];
  unsigned short* Xs = (unsigned short*)(smem + SM_X);   // [128][136]
  unsigned short* As = (unsigned short*)(smem + SM_X);   // [128][40] overlay
  unsigned short* Ws = (unsigned short*)(smem + SM_W);   // [128][136] (layer0: stride 40)
  float* mArr = (float*)(smem + SM_M);
  float* P    = (float*)(smem + SM_P);

  const int tid = threadIdx.x;
  const int b   = blockIdx.x >> 3;
  const int c0  = (blockIdx.x & 7) << 2;

  // ---- stage: mask, params, pair features (As), WT0 ----
  if (tid < 128) {
    int r = tid & 31, cl = tid >> 5;
    float a = adj[(b * 32 + r) * 32 + c0 + cl];
    mArr[tid] = (a > 0.f && a < 1.f) ? 1.f : 0.f;
  }
  for (int i = tid; i < 1152; i += 256) {
    int layer = i / 384, rem = i - layer * 384;
    int kind = rem >> 7, hh = rem & 127;
    float val;
    if (layer == 0)
      val = (kind == 0) ? lin1_b[hh] : (kind == 1 ? ln1_g[hh] : ln1_beta[hh]);
    else {
      int l = layer - 1;
      val = (kind == 0) ? linh_b[l * 128 + hh]
                        : (kind == 1 ? lnh_g[l * 128 + hh] : lnh_b[l * 128 + hh]);
    }
    P[i] = val;
  }
  for (int i = tid; i < 4096; i += 256) {
    int p = i >> 5, k = i & 31;
    int r = p & 31, cl = p >> 5;
    float val;
    if (k < 15) {
      val = node_obs[(b * 32 + r) * 16 + k];
    } else if (k < 31) {
      int ent = (int)node_obs[(b * 32 + r) * 16 + 15];
      val = ent_emb[ent * 16 + (k - 15)];
    } else {
      float a = adj[(b * 32 + r) * 32 + c0 + cl];
      val = (a > 0.f && a < 1.f) ? a : 0.f;   // e = adj * mask
    }
    As[p * 40 + k] = f2bf(val);
  }
  for (int i = tid; i < 1024; i += 256) {   // WT0 -> Ws (stride 40)
    int n = i >> 3, kc = i & 7;
    ushort4 w = ((const ushort4*)WT0)[i];
    *(ushort4*)(Ws + n * 40 + kc * 4) = w;
  }
  __syncthreads();

  const int lane = tid & 63, li = lane & 15, quad = lane >> 4, wv = tid >> 6;
  f32x4 acc[2][8];

  // ---- layer 0: pair(32) @ lin1_w -> relu -> LN1 ----
#pragma unroll
  for (int ti = 0; ti < 2; ++ti)
#pragma unroll
    for (int tj = 0; tj < 8; ++tj)
#pragma unroll
      for (int q = 0; q < 4; ++q) acc[ti][tj][q] = 0.f;
  {
    bf16x8 a0 = lds_frag(As + (32 * wv + li) * 40 + quad * 8);
    bf16x8 a1 = lds_frag(As + (32 * wv + 16 + li) * 40 + quad * 8);
#pragma unroll
    for (int tj = 0; tj < 8; ++tj) {
      bf16x8 bb = lds_frag(Ws + (tj * 16 + li) * 40 + quad * 8);
      acc[0][tj] = mfma16(a0, bb, acc[0][tj]);
      acc[1][tj] = mfma16(a1, bb, acc[1][tj]);
    }
  }
  __syncthreads();   // As overlaps other waves' Xs rows: drain all A/B reads first
  epilogue_store(acc, P, 0, Xs, wv, li, quad);

  for (int i = tid; i < 2048; i += 256) {   // WT1 -> Ws (stride 136)
    int n = i >> 4, ch = i & 15;
    uint4 w = ((const uint4*)WT1)[i];
    *(uint4*)(Ws + n * 136 + ch * 8) = w;
  }
  __syncthreads();

  // ---- layer 1 ----
#pragma unroll
  for (int ti = 0; ti < 2; ++ti)
#pragma unroll
    for (int tj = 0; tj < 8; ++tj)
#pragma unroll
      for (int q = 0; q < 4; ++q) acc[ti][tj][q] = 0.f;
#pragma unroll
  for (int s = 0; s < 4; ++s) {
    bf16x8 a0 = lds_frag(Xs + (32 * wv + li) * 136 + s * 32 + quad * 8);
    bf16x8 a1 = lds_frag(Xs + (32 * wv + 16 + li) * 136 + s * 32 + quad * 8);
#pragma unroll
    for (int tj = 0; tj < 8; ++tj) {
      bf16x8 bb = lds_frag(Ws + (tj * 16 + li) * 136 + s * 32 + quad * 8);
      acc[0][tj] = mfma16(a0, bb, acc[0][tj]);
      acc[1][tj] = mfma16(a1, bb, acc[1][tj]);
    }
  }
  epilogue_store(acc, P, 384, Xs, wv, li, quad);  // own rows only: no cross-wave hazard
  __syncthreads();

  for (int i = tid; i < 2048; i += 256) {   // WT2 -> Ws
    int n = i >> 4, ch = i & 15;
    uint4 w = ((const uint4*)WT2)[i];
    *(uint4*)(Ws + n * 136 + ch * 8) = w;
  }
  __syncthreads();

  // ---- layer 2 + masked aggregate over r -> h[b, c0+wv, :] ----
#pragma unroll
  for (int ti = 0; ti < 2; ++ti)
#pragma unroll
    for (int tj = 0; tj < 8; ++tj)
#pragma unroll
      for (int q = 0; q < 4; ++q) acc[ti][tj][q] = 0.f;
#pragma unroll
  for (int s = 0; s < 4; ++s) {
    bf16x8 a0 = lds_frag(Xs + (32 * wv + li) * 136 + s * 32 + quad * 8);
    bf16x8 a1 = lds_frag(Xs + (32 * wv + 16 + li) * 136 + s * 32 + quad * 8);
#pragma unroll
    for (int tj = 0; tj < 8; ++tj) {
      bf16x8 bb = lds_frag(Ws + (tj * 16 + li) * 136 + s * 32 + quad * 8);
      acc[0][tj] = mfma16(a0, bb, acc[0][tj]);
      acc[1][tj] = mfma16(a1, bb, acc[1][tj]);
    }
  }
  epilogue_agg(acc, P, 768, mArr, hout + (b * 32 + c0 + wv) * 128, wv, li, quad);
}

// ---------------------------------------------------------------------------
// k_score: s[row] = relu(h@fc2a + b)@fc2b + b2, 128 rows per block via MFMA.
// ---------------------------------------------------------------------------
#define SC_TOTAL 70656
__global__ __launch_bounds__(256, 2)
void k_score(const float* __restrict__ hws, const unsigned short* __restrict__ WT3,
             const float* __restrict__ fc2a_b, const float* __restrict__ fc2b_w,
             const float* __restrict__ fc2b_b, float* __restrict__ sws) {
  __shared__ alignas(16) char smem[SC_TOTAL];
  unsigned short* Xs = (unsigned short*)smem;
  unsigned short* Ws = (unsigned short*)(smem + 34816);
  float* P = (float*)(smem + 69632);
  const int tid = threadIdx.x;
  const int row0 = blockIdx.x * 128;

  for (int i = tid; i < 4096; i += 256) {
    int row = i >> 5, cc = i & 31;
    float4 hv = ((const float4*)hws)[(row0 + row) * 32 + cc];
    ushort4 o;
    o.x = f2bf(hv.x); o.y = f2bf(hv.y); o.z = f2bf(hv.z); o.w = f2bf(hv.w);
    *(ushort4*)(Xs + row * 136 + cc * 4) = o;
  }
  for (int i = tid; i < 2048; i += 256) {
    int n = i >> 4, ch = i & 15;
    uint4 w = ((const uint4*)WT3)[i];
    *(uint4*)(Ws + n * 136 + ch * 8) = w;
  }
  if (tid < 128) { P[tid] = fc2a_b[tid]; P[128 + tid] = fc2b_w[tid]; }
  __syncthreads();

  const int lane = tid & 63, li = lane & 15, quad = lane >> 4, wv = tid >> 6;
  f32x4 acc[2][8];
#pragma unroll
  for (int ti = 0; ti < 2; ++ti)
#pragma unroll
    for (int tj = 0; tj < 8; ++tj)
#pragma unroll
      for (int q = 0; q < 4; ++q) acc[ti][tj][q] = 0.f;
#pragma unroll
  for (int s = 0; s < 4; ++s) {
    bf16x8 a0 = lds_frag(Xs + (32 * wv + li) * 136 + s * 32 + quad * 8);
    bf16x8 a1 = lds_frag(Xs + (32 * wv + 16 + li) * 136 + s * 32 + quad * 8);
#pragma unroll
    for (int tj = 0; tj < 8; ++tj) {
      bf16x8 bb = lds_frag(Ws + (tj * 16 + li) * 136 + s * 32 + quad * 8);
      acc[0][tj] = mfma16(a0, bb, acc[0][tj]);
      acc[1][tj] = mfma16(a1, bb, acc[1][tj]);
    }
  }
  float bs[8], w2[8];
#pragma unroll
  for (int tj = 0; tj < 8; ++tj) {
    bs[tj] = P[tj * 16 + li];
    w2[tj] = P[128 + tj * 16 + li];
  }
  float b2 = fc2b_b[0];
#pragma unroll
  for (int ti = 0; ti < 2; ++ti) {
#pragma unroll
    for (int rg = 0; rg < 4; ++rg) {
      float t = 0.f;
#pragma unroll
      for (int tj = 0; tj < 8; ++tj) {
        float x = acc[ti][tj][rg] + bs[tj];
        x = fmaxf(x, 0.f);
        t += x * w2[tj];
      }
#pragma unroll
      for (int m = 1; m < 16; m <<= 1) t += __shfl_xor(t, m);
      if (li == 0) sws[row0 + 32 * wv + ti * 16 + quad * 4 + rg] = t + b2;
    }
  }
}

// ---------------------------------------------------------------------------
// k_stats: global softmax max & sum over 16384 scores (single block).
// ---------------------------------------------------------------------------
__global__ __launch_bounds__(1024)
void k_stats(const float* __restrict__ sws, float* __restrict__ stats) {
  __shared__ float red[1024];
  const int tid = threadIdx.x;
  float m = -3.0e38f;
  for (int i = tid; i < 16384; i += 1024) m = fmaxf(m, sws[i]);
  red[tid] = m;
  __syncthreads();
  for (int st = 512; st > 0; st >>= 1) {
    if (tid < st) red[tid] = fmaxf(red[tid], red[tid + st]);
    __syncthreads();
  }
  float mx = red[0];
  __syncthreads();
  float sm = 0.f;
  for (int i = tid; i < 16384; i += 1024) sm += __expf(sws[i] - mx);
  red[tid] = sm;
  __syncthreads();
  for (int st = 512; st > 0; st >>= 1) {
    if (tid < st) red[tid] += red[tid + st];
    __syncthreads();
  }
  if (tid == 0) { stats[0] = mx; stats[1] = red[0]; }
}

// ---------------------------------------------------------------------------
// k_final: only the 512 gathered rows need fc3/ln3/fc4/ln4.
// ---------------------------------------------------------------------------
__global__ __launch_bounds__(128)
void k_final(const float* __restrict__ hws, const float* __restrict__ sws,
             const float* __restrict__ stats, const int* __restrict__ agent_id,
             const float* __restrict__ fc3_w, const float* __restrict__ fc3_b,
             const float* __restrict__ ln3_g, const float* __restrict__ ln3_b,
             const float* __restrict__ fc4_w, const float* __restrict__ fc4_b,
             const float* __restrict__ ln4_g, const float* __restrict__ ln4_b,
             float* __restrict__ out) {
  __shared__ float xrow[128];
  __shared__ float red[8];
  const int tid = threadIdx.x;
  const int b = blockIdx.x;
  const int row = b * 32 + agent_id[b];
  xrow[tid] = hws[row * 128 + tid];
  __syncthreads();
  float t = fc3_b[tid];
  for (int k = 0; k < 128; ++k) t += xrow[k] * fc3_w[k * 128 + tid];
  t = fmaxf(t, 0.f);
  float s1 = t, s2 = t * t;
#pragma unroll
  for (int m = 1; m < 64; m <<= 1) { s1 += __shfl_xor(s1, m); s2 += __shfl_xor(s2, m); }
  if ((tid & 63) == 0) { red[(tid >> 6) * 2] = s1; red[(tid >> 6) * 2 + 1] = s2; }
  __syncthreads();
  s1 = red[0] + red[2]; s2 = red[1] + red[3];
  float mean = s1 * 0.0078125f;
  float var  = s2 * 0.0078125f - mean * mean;
  float inv  = rsqrtf(var + 1e-5f);
  float v = (t - mean) * inv * ln3_g[tid] + ln3_b[tid];
  float alpha = __expf(sws[row] - stats[0]) / stats[1];
  __syncthreads();
  xrow[tid] = alpha * v;
  __syncthreads();
  float x = fc4_b[tid];
  for (int k = 0; k < 128; ++k) x += xrow[k] * fc4_w[k * 128 + tid];
  x = fmaxf(x, 0.f);
  s1 = x; s2 = x * x;
#pragma unroll
  for (int m = 1; m < 64; m <<= 1) { s1 += __shfl_xor(s1, m); s2 += __shfl_xor(s2, m); }
  if ((tid & 63) == 0) { red[4 + (tid >> 6) * 2] = s1; red[5 + (tid >> 6) * 2] = s2; }
  __syncthreads();
  s1 = red[4] + red[6]; s2 = red[5] + red[7];
  mean = s1 * 0.0078125f;
  var  = s2 * 0.0078125f - mean * mean;
  inv  = rsqrtf(var + 1e-5f);
  out[b * 128 + tid] = (x - mean) * inv * ln4_g[tid] + ln4_b[tid];
}

// ---------------------------------------------------------------------------
extern "C" void kernel_launch(void* const* d_in, const int* in_sizes, int n_in,
                              void* d_out, int out_size, void* d_ws, size_t ws_size,
                              hipStream_t stream) {
  (void)in_sizes; (void)n_in; (void)out_size; (void)ws_size;
  const float* node_obs = (const float*)d_in[0];
  const float* adj      = (const float*)d_in[1];
  const int*   agent_id = (const int*)d_in[2];
  const float* ent_emb  = (const float*)d_in[3];
  const float* lin1_w   = (const float*)d_in[4];
  const float* lin1_b   = (const float*)d_in[5];
  const float* ln1_g    = (const float*)d_in[6];
  const float* ln1_beta = (const float*)d_in[7];
  const float* linh_w   = (const float*)d_in[8];
  const float* linh_b   = (const float*)d_in[9];
  const float* lnh_g    = (const float*)d_in[10];
  const float* lnh_b    = (const float*)d_in[11];
  const float* fc2a_w   = (const float*)d_in[12];
  const float* fc2a_b   = (const float*)d_in[13];
  const float* fc2b_w   = (const float*)d_in[14];
  const float* fc2b_b   = (const float*)d_in[15];
  const float* fc3_w    = (const float*)d_in[16];
  const float* fc3_b    = (const float*)d_in[17];
  const float* ln3_g    = (const float*)d_in[18];
  const float* ln3_b    = (const float*)d_in[19];
  const float* fc4_w    = (const float*)d_in[20];
  const float* fc4_b    = (const float*)d_in[21];
  const float* ln4_g    = (const float*)d_in[22];
  const float* ln4_b    = (const float*)d_in[23];
  float* out = (float*)d_out;

  char* ws = (char*)d_ws;
  float* hws            = (float*)(ws);                 // 16384*128 f32 = 8 MB
  float* sws            = (float*)(ws + 8388608);       // 16384 f32
  float* stats          = (float*)(ws + 8454144);       // 2 f32
  unsigned short* WT0   = (unsigned short*)(ws + 8454208);  // 128*32 bf16
  unsigned short* WT1   = (unsigned short*)(ws + 8462400);  // 128*128 bf16
  unsigned short* WT2   = (unsigned short*)(ws + 8495168);
  unsigned short* WT3   = (unsigned short*)(ws + 8527936);

  k_prep<<<64, 256, 0, stream>>>(lin1_w, linh_w, fc2a_w, WT0, WT1, WT2, WT3);
  k_pair<<<4096, 256, 0, stream>>>(node_obs, adj, ent_emb, lin1_b, ln1_g, ln1_beta,
                                   linh_b, lnh_g, lnh_b, WT0, WT1, WT2, hws);
  k_score<<<128, 256, 0, stream>>>(hws, WT3, fc2a_b, fc2b_w, fc2b_b, sws);
  k_stats<<<1, 1024, 0, stream>>>(sws, stats);
  k_final<<<512, 128, 0, stream>>>(hws, sws, stats, agent_id,
                                   fc3_w, fc3_b, ln3_g, ln3_b,
                                   fc4_w, fc4_b, ln4_g, ln4_b, out);
}

// Round 2
// 228.019 us; speedup vs baseline: 1.3304x; 1.3304x over previous
//
#include <hip/hip_runtime.h>
#include <hip/hip_bf16.h>

// ---------------------------------------------------------------------------
// GNNBase: B=512, N=32, F=16, H=128, E=16, NE=3, L=2, D0=32
//   k_prep : build bf16 xj table [16384][32] + pre-padded bf16 W^T images in ws
//   k_pair : per (b, 4 c's): layer0 (per-wave 32x32 A-tile w/ patched e column)
//            + 2 hidden layers, MFMA 16x16x32, LN fused in C-frag registers,
//            split-K weight staging via global_load_lds (3 blocks/CU),
//            masked aggregate -> hb (bf16) + hsel (f32, agent rows only)
//   k_score: s = relu(h@fc2a+b)@fc2b+b2 (MFMA, 128-row tiles)
//   k_stats: softmax max/sum over 16384 scores
//   k_final: 512 agent rows: v=LN(relu(h@fc3)), out=LN(relu(alpha*v@fc4))
// ---------------------------------------------------------------------------

typedef __attribute__((ext_vector_type(8))) __bf16 bf16x8;
typedef __attribute__((ext_vector_type(4))) float  f32x4;

__device__ __forceinline__ unsigned short f2bf(float f) {
  union { float f; unsigned u; } v; v.f = f;
  unsigned u = v.u;
  u += 0x7FFFu + ((u >> 16) & 1u);   // RTNE
  return (unsigned short)(u >> 16);
}

__device__ __forceinline__ unsigned pk2bf(float a, float b) {
  union { __hip_bfloat162 h; unsigned u; } cv;
  cv.h = __float22bfloat162_rn(make_float2(a, b));   // .x -> low 16
  return cv.u;
}

__device__ __forceinline__ bf16x8 lds_frag(const unsigned short* p) {
  union { uint4 u; bf16x8 v; } x;
  x.u = *(const uint4*)p;            // ds_read_b128
  return x.v;
}

__device__ __forceinline__ f32x4 mfma16(bf16x8 a, bf16x8 b, f32x4 c) {
  return __builtin_amdgcn_mfma_f32_16x16x32_bf16(a, b, c, 0, 0, 0);
}

// async global->LDS, 16 B per lane. LDS dest = wave-uniform base + lane*16.
__device__ __forceinline__ void gll16(const void* g, void* l) {
  __builtin_amdgcn_global_load_lds(
      (const __attribute__((address_space(1))) unsigned int*)(unsigned long long)g,
      (__attribute__((address_space(3))) unsigned int*)(unsigned int)(unsigned long long)l,
      16, 0, 0);
}

// copy a contiguous 18432-B pre-padded weight image into LDS (256 threads)
__device__ __forceinline__ void stage18432(const char* g, char* l, int tid) {
  int off = tid * 16;
  gll16(g + off,         l + off);
  gll16(g + off + 4096,  l + off + 4096);
  gll16(g + off + 8192,  l + off + 8192);
  gll16(g + off + 12288, l + off + 12288);
  if (tid < 128) gll16(g + off + 16384, l + off + 16384);
}

// ---------------------------------------------------------------------------
// workspace layout (bytes)
// ---------------------------------------------------------------------------
#define WS_HB    0           // bf16 h [16384][128]            4194304
#define WS_HSEL  4194304     // f32  h agent rows [512][128]    262144
#define WS_SWS   4456448     // f32 scores [16384]               65536
#define WS_STATS 4521984     // f32 [2]                            256
#define WS_XJB   4522240     // bf16 xj [16384][32]            1048576
#define WS_WT0P  5570816     // bf16 lin1 W^T [128][40]          10240
#define WS_W1P   5581056     // bf16 linh0 W^T [2][128][72]      36864
#define WS_W2P   5617920     // bf16 linh1 W^T [2][128][72]      36864
#define WS_WT3P  5654784     // bf16 fc2a W^T [128][136]         34816

// ---------------------------------------------------------------------------
// k_prep: one flat grid builds xjb + all padded weight images.
// ---------------------------------------------------------------------------
#define PREP_N0 524288                 // xjb elements
#define PREP_N1 (PREP_N0 + 5120)      // + WT0p [128][40]
#define PREP_N2 (PREP_N1 + 36864)     // + W1p/W2p [2l][2h][128][72]
#define PREP_N3 (PREP_N2 + 17408)     // + WT3p [128][136]

__global__ void k_prep(const float* __restrict__ node_obs, const float* __restrict__ ent_emb,
                       const float* __restrict__ lin1_w, const float* __restrict__ linh_w,
                       const float* __restrict__ fc2a_w, char* __restrict__ ws) {
  int idx = blockIdx.x * 256 + threadIdx.x;
  unsigned short* xjb  = (unsigned short*)(ws + WS_XJB);
  unsigned short* WT0p = (unsigned short*)(ws + WS_WT0P);
  unsigned short* W1p  = (unsigned short*)(ws + WS_W1P);
  unsigned short* W2p  = (unsigned short*)(ws + WS_W2P);
  unsigned short* WT3p = (unsigned short*)(ws + WS_WT3P);
  if (idx < PREP_N0) {
    int row = idx >> 5, k = idx & 31;
    float val;
    if (k < 15) val = node_obs[row * 16 + k];
    else if (k < 31) {
      int ent = (int)node_obs[row * 16 + 15];
      val = ent_emb[ent * 16 + (k - 15)];
    } else val = 0.f;   // e slot, patched per-wave in k_pair
    xjb[idx] = f2bf(val);
  } else if (idx < PREP_N1) {
    int r = idx - PREP_N0;
    int n = r / 40, kk = r - n * 40;
    WT0p[n * 40 + kk] = (kk < 32) ? f2bf(lin1_w[kk * 128 + n]) : (unsigned short)0;
  } else if (idx < PREP_N2) {
    int r = idx - PREP_N1;
    int l = r / 18432; r -= l * 18432;
    int h = r / 9216;  r -= h * 9216;
    int n = r / 72;    int kk = r - n * 72;
    unsigned short v = (kk < 64) ? f2bf(linh_w[l * 16384 + (h * 64 + kk) * 128 + n])
                                 : (unsigned short)0;
    (l ? W2p : W1p)[h * 9216 + n * 72 + kk] = v;
  } else if (idx < PREP_N3) {
    int r = idx - PREP_N2;
    int n = r / 136, kk = r - n * 136;
    WT3p[n * 136 + kk] = (kk < 128) ? f2bf(fc2a_w[kk * 128 + n]) : (unsigned short)0;
  }
}

// ---------------------------------------------------------------------------
// epilogues. C-frag (16x16x32): col = tj*16+(lane&15), row = ti*16+quad*4+reg.
// params read straight from global (L2-hot, same lines for every block).
// ---------------------------------------------------------------------------
__device__ __forceinline__ void zero_acc(f32x4 (&acc)[2][8]) {
#pragma unroll
  for (int ti = 0; ti < 2; ++ti)
#pragma unroll
    for (int tj = 0; tj < 8; ++tj)
#pragma unroll
      for (int q = 0; q < 4; ++q) acc[ti][tj][q] = 0.f;
}

__device__ __forceinline__ void epilogue_store(f32x4 (&acc)[2][8],
    const float* __restrict__ gb, const float* __restrict__ gg,
    const float* __restrict__ gbe,
    unsigned short* Xs, int wv, int li, int quad) {
  float bs[8], g[8], be[8];
#pragma unroll
  for (int tj = 0; tj < 8; ++tj) {
    int col = tj * 16 + li;
    bs[tj] = gb[col]; g[tj] = gg[col]; be[tj] = gbe[col];
  }
#pragma unroll
  for (int ti = 0; ti < 2; ++ti) {
#pragma unroll
    for (int rg = 0; rg < 4; ++rg) {
      float v[8], s1 = 0.f, s2 = 0.f;
#pragma unroll
      for (int tj = 0; tj < 8; ++tj) {
        float x = acc[ti][tj][rg] + bs[tj];
        x = fmaxf(x, 0.f);
        v[tj] = x; s1 += x; s2 += x * x;
      }
#pragma unroll
      for (int m = 1; m < 16; m <<= 1) { s1 += __shfl_xor(s1, m); s2 += __shfl_xor(s2, m); }
      float mean = s1 * 0.0078125f;
      float var  = s2 * 0.0078125f - mean * mean;
      float inv  = rsqrtf(var + 1e-5f);
      int row = 32 * wv + ti * 16 + quad * 4 + rg;
      float o[8];
#pragma unroll
      for (int tj = 0; tj < 8; ++tj) o[tj] = (v[tj] - mean) * inv * g[tj] + be[tj];
#pragma unroll
      for (int tj = 0; tj < 8; tj += 2) {
        unsigned u = pk2bf(o[tj], o[tj + 1]);
        Xs[row * 136 + tj * 16 + li]       = (unsigned short)(u & 0xffffu);
        Xs[row * 136 + (tj + 1) * 16 + li] = (unsigned short)(u >> 16);
      }
    }
  }
}

// final layer: LN then masked sum over the 32 rows -> one h row per wave.
__device__ __forceinline__ void epilogue_agg(f32x4 (&acc)[2][8],
    const float* __restrict__ gb, const float* __restrict__ gg,
    const float* __restrict__ gbe,
    float mflag /* lane r<32 holds mask[r] */,
    unsigned short* __restrict__ hb_row, float* __restrict__ hsel_row,
    int li, int quad) {
  float bs[8], g[8], be[8], cs[8];
#pragma unroll
  for (int tj = 0; tj < 8; ++tj) {
    int col = tj * 16 + li;
    bs[tj] = gb[col]; g[tj] = gg[col]; be[tj] = gbe[col];
    cs[tj] = 0.f;
  }
#pragma unroll
  for (int ti = 0; ti < 2; ++ti) {
#pragma unroll
    for (int rg = 0; rg < 4; ++rg) {
      float v[8], s1 = 0.f, s2 = 0.f;
#pragma unroll
      for (int tj = 0; tj < 8; ++tj) {
        float x = acc[ti][tj][rg] + bs[tj];
        x = fmaxf(x, 0.f);
        v[tj] = x; s1 += x; s2 += x * x;
      }
#pragma unroll
      for (int m = 1; m < 16; m <<= 1) { s1 += __shfl_xor(s1, m); s2 += __shfl_xor(s2, m); }
      float mean = s1 * 0.0078125f;
      float var  = s2 * 0.0078125f - mean * mean;
      float inv  = rsqrtf(var + 1e-5f);
      int row = ti * 16 + quad * 4 + rg;
      float mk = __shfl(mflag, row);   // mask[row] lives in lane `row`
#pragma unroll
      for (int tj = 0; tj < 8; ++tj)
        cs[tj] += mk * ((v[tj] - mean) * inv * g[tj] + be[tj]);
    }
  }
#pragma unroll
  for (int tj = 0; tj < 8; ++tj) {
    cs[tj] += __shfl_xor(cs[tj], 16);
    cs[tj] += __shfl_xor(cs[tj], 32);
  }
  if (quad == 0) {
#pragma unroll
    for (int tj = 0; tj < 8; tj += 2) {
      unsigned u = pk2bf(cs[tj], cs[tj + 1]);
      hb_row[tj * 16 + li]       = (unsigned short)(u & 0xffffu);
      hb_row[(tj + 1) * 16 + li] = (unsigned short)(u >> 16);
    }
    if (hsel_row) {
#pragma unroll
      for (int tj = 0; tj < 8; ++tj) hsel_row[tj * 16 + li] = cs[tj];
    }
  }
}

// ---------------------------------------------------------------------------
// k_pair. LDS: Xs [128][136] bf16 (first 10240 B overlaid by 4 per-wave
// 32x40 xj tiles during layer 0) + Wh [128][72] bf16 half-K weight buffer.
// 53248 B -> 3 blocks/CU (launch_bounds(256,3)).
// ---------------------------------------------------------------------------
#define SMP_W 34816
#define SMP_TOTAL 53248

__device__ __forceinline__ void mfma_half(f32x4 (&acc)[2][8],
    const unsigned short* Xs, const unsigned short* Wh,
    int xoff, int wv, int li, int quad) {
#pragma unroll
  for (int s = 0; s < 2; ++s) {
    bf16x8 a0 = lds_frag(Xs + (32 * wv + li) * 136 + xoff + s * 32 + quad * 8);
    bf16x8 a1 = lds_frag(Xs + (32 * wv + 16 + li) * 136 + xoff + s * 32 + quad * 8);
#pragma unroll
    for (int tj = 0; tj < 8; ++tj) {
      bf16x8 bb = lds_frag(Wh + (tj * 16 + li) * 72 + s * 32 + quad * 8);
      acc[0][tj] = mfma16(a0, bb, acc[0][tj]);
      acc[1][tj] = mfma16(a1, bb, acc[1][tj]);
    }
  }
}

__global__ __launch_bounds__(256, 3)
void k_pair(const float* __restrict__ adj, const int* __restrict__ agent_id,
            const float* __restrict__ lin1_b, const float* __restrict__ ln1_g,
            const float* __restrict__ ln1_beta,
            const float* __restrict__ linh_b, const float* __restrict__ lnh_g,
            const float* __restrict__ lnh_b,
            char* __restrict__ ws) {
  __shared__ alignas(16) char smem[SMP_TOTAL];
  unsigned short* Xs = (unsigned short*)smem;
  unsigned short* Wh = (unsigned short*)(smem + SMP_W);

  const unsigned short* xjb = (const unsigned short*)(ws + WS_XJB);
  const char* WT0p = ws + WS_WT0P;
  const char* W1p  = ws + WS_W1P;
  const char* W2p  = ws + WS_W2P;

  const int tid  = threadIdx.x;
  const int b    = blockIdx.x >> 3;
  const int c0   = (blockIdx.x & 7) << 2;
  const int lane = tid & 63, li = lane & 15, quad = lane >> 4, wv = tid >> 6;
  const int c    = c0 + wv;

  // ---- phase 0: per-wave xj tile (stride 40) + WT0p via global_load_lds ----
  {
    const uint4* src = (const uint4*)xjb;
    char* tile = smem + wv * 2560;
    int r0 = lane >> 2, p0 = lane & 3;
    uint4 v0 = src[(b * 32 + r0) * 4 + p0];
    uint4 v1 = src[(b * 32 + 16 + r0) * 4 + p0];
    *(uint4*)(tile + r0 * 80 + p0 * 16) = v0;
    *(uint4*)(tile + (16 + r0) * 80 + p0 * 16) = v1;
  }
  // WT0p image: 10240 B contiguous
  {
    int off = tid * 16;
    gll16(WT0p + off, smem + SMP_W + off);
    gll16(WT0p + off + 4096, smem + SMP_W + off + 4096);
    if (tid < 128) gll16(WT0p + off + 8192, smem + SMP_W + off + 8192);
  }
  // e column patch + mask flag (lane r<32 keeps mask[r] for the aggregate)
  float mflag = 0.f;
  if (lane < 32) {
    float a = adj[(b * 32 + lane) * 32 + c];
    float e = (a > 0.f && a < 1.f) ? a : 0.f;
    mflag = (e != 0.f) ? 1.f : 0.f;
    ((unsigned short*)(smem + wv * 2560 + lane * 80))[31] = f2bf(e);
  }
  __syncthreads();

  f32x4 acc[2][8];

  // ---- layer 0: [32 pair rows] x [K=32] @ lin1 ----
  zero_acc(acc);
  {
    const unsigned short* xt = (const unsigned short*)(smem + wv * 2560);
    bf16x8 a0 = lds_frag(xt + li * 40 + quad * 8);
    bf16x8 a1 = lds_frag(xt + (li + 16) * 40 + quad * 8);
#pragma unroll
    for (int tj = 0; tj < 8; ++tj) {
      bf16x8 bb = lds_frag(Wh + (tj * 16 + li) * 40 + quad * 8);
      acc[0][tj] = mfma16(a0, bb, acc[0][tj]);
      acc[1][tj] = mfma16(a1, bb, acc[1][tj]);
    }
  }
  __syncthreads();                       // drain A/B reads before overwrites
  stage18432(W1p, smem + SMP_W, tid);    // W1 half0 in flight during epilogue
  epilogue_store(acc, lin1_b, ln1_g, ln1_beta, Xs, wv, li, quad);
  __syncthreads();

  // ---- hidden layer 1 ----
  zero_acc(acc);
  mfma_half(acc, Xs, Wh, 0, wv, li, quad);
  __syncthreads();
  stage18432(W1p + 18432, smem + SMP_W, tid);
  __syncthreads();
  mfma_half(acc, Xs, Wh, 64, wv, li, quad);
  __syncthreads();
  stage18432(W2p, smem + SMP_W, tid);
  epilogue_store(acc, linh_b, lnh_g, lnh_b, Xs, wv, li, quad);
  __syncthreads();

  // ---- hidden layer 2 + masked aggregate ----
  zero_acc(acc);
  mfma_half(acc, Xs, Wh, 0, wv, li, quad);
  __syncthreads();
  stage18432(W2p + 18432, smem + SMP_W, tid);
  __syncthreads();
  mfma_half(acc, Xs, Wh, 64, wv, li, quad);

  unsigned short* hb  = (unsigned short*)(ws + WS_HB) + (b * 32 + c) * 128;
  float* hsel = (c == agent_id[b]) ? ((float*)(ws + WS_HSEL) + b * 128) : nullptr;
  epilogue_agg(acc, linh_b + 128, lnh_g + 128, lnh_b + 128,
               mflag, hb, hsel, li, quad);
}

// ---------------------------------------------------------------------------
// k_score: s[row] = relu(h@fc2a+b)@fc2b + b2, 128 rows/block via MFMA.
// ---------------------------------------------------------------------------
#define SC_TOTAL 70656
__global__ __launch_bounds__(256, 2)
void k_score(const char* __restrict__ ws,
             const float* __restrict__ fc2a_b, const float* __restrict__ fc2b_w,
             const float* __restrict__ fc2b_b) {
  __shared__ alignas(16) char smem[SC_TOTAL];
  unsigned short* Xs = (unsigned short*)smem;
  unsigned short* Ws = (unsigned short*)(smem + 34816);
  float* P = (float*)(smem + 69632);
  const int tid = threadIdx.x;
  const int row0 = blockIdx.x * 128;
  const uint4* hb4 = (const uint4*)(ws + WS_HB);
  const char* WT3p = ws + WS_WT3P;
  float* sws = (float*)((char*)ws + WS_SWS);

  for (int i = tid; i < 2048; i += 256) {      // hb rows -> padded Xs
    int row = i >> 4, ch = i & 15;
    uint4 v = hb4[(row0 + row) * 16 + ch];
    *(uint4*)(Xs + row * 136 + ch * 8) = v;
  }
  {                                            // WT3p image: 34816 B
    int off = tid * 16;
#pragma unroll
    for (int it = 0; it < 8; ++it) gll16(WT3p + off + it * 4096, smem + 34816 + off + it * 4096);
    if (tid < 128) gll16(WT3p + off + 32768, smem + 34816 + off + 32768);
  }
  if (tid < 128) { P[tid] = fc2a_b[tid]; P[128 + tid] = fc2b_w[tid]; }
  __syncthreads();

  const int lane = tid & 63, li = lane & 15, quad = lane >> 4, wv = tid >> 6;
  f32x4 acc[2][8];
  zero_acc(acc);
#pragma unroll
  for (int s = 0; s < 4; ++s) {
    bf16x8 a0 = lds_frag(Xs + (32 * wv + li) * 136 + s * 32 + quad * 8);
    bf16x8 a1 = lds_frag(Xs + (32 * wv + 16 + li) * 136 + s * 32 + quad * 8);
#pragma unroll
    for (int tj = 0; tj < 8; ++tj) {
      bf16x8 bb = lds_frag(Ws + (tj * 16 + li) * 136 + s * 32 + quad * 8);
      acc[0][tj] = mfma16(a0, bb, acc[0][tj]);
      acc[1][tj] = mfma16(a1, bb, acc[1][tj]);
    }
  }
  float bs[8], w2[8];
#pragma unroll
  for (int tj = 0; tj < 8; ++tj) {
    bs[tj] = P[tj * 16 + li];
    w2[tj] = P[128 + tj * 16 + li];
  }
  float b2 = fc2b_b[0];
#pragma unroll
  for (int ti = 0; ti < 2; ++ti) {
#pragma unroll
    for (int rg = 0; rg < 4; ++rg) {
      float t = 0.f;
#pragma unroll
      for (int tj = 0; tj < 8; ++tj) {
        float x = acc[ti][tj][rg] + bs[tj];
        x = fmaxf(x, 0.f);
        t += x * w2[tj];
      }
#pragma unroll
      for (int m = 1; m < 16; m <<= 1) t += __shfl_xor(t, m);
      if (li == 0) sws[row0 + 32 * wv + ti * 16 + quad * 4 + rg] = t + b2;
    }
  }
}

// ---------------------------------------------------------------------------
// k_stats: softmax max & sum over 16384 scores (single block).
// ---------------------------------------------------------------------------
__global__ __launch_bounds__(1024)
void k_stats(char* __restrict__ ws) {
  const float* sws = (const float*)(ws + WS_SWS);
  float* stats = (float*)(ws + WS_STATS);
  __shared__ float red[1024];
  const int tid = threadIdx.x;
  float m = -3.0e38f;
  for (int i = tid; i < 16384; i += 1024) m = fmaxf(m, sws[i]);
  red[tid] = m;
  __syncthreads();
  for (int st = 512; st > 0; st >>= 1) {
    if (tid < st) red[tid] = fmaxf(red[tid], red[tid + st]);
    __syncthreads();
  }
  float mx = red[0];
  __syncthreads();
  float sm = 0.f;
  for (int i = tid; i < 16384; i += 1024) sm += __expf(sws[i] - mx);
  red[tid] = sm;
  __syncthreads();
  for (int st = 512; st > 0; st >>= 1) {
    if (tid < st) red[tid] += red[tid + st];
    __syncthreads();
  }
  if (tid == 0) { stats[0] = mx; stats[1] = red[0]; }
}

// ---------------------------------------------------------------------------
// k_final: 512 agent rows only.
// ---------------------------------------------------------------------------
__global__ __launch_bounds__(128)
void k_final(const char* __restrict__ ws, const int* __restrict__ agent_id,
             const float* __restrict__ fc3_w, const float* __restrict__ fc3_b,
             const float* __restrict__ ln3_g, const float* __restrict__ ln3_b,
             const float* __restrict__ fc4_w, const float* __restrict__ fc4_b,
             const float* __restrict__ ln4_g, const float* __restrict__ ln4_b,
             float* __restrict__ out) {
  const float* hsel  = (const float*)(ws + WS_HSEL);
  const float* sws   = (const float*)(ws + WS_SWS);
  const float* stats = (const float*)(ws + WS_STATS);
  __shared__ float xrow[128];
  __shared__ float red[8];
  const int tid = threadIdx.x;
  const int b = blockIdx.x;
  xrow[tid] = hsel[b * 128 + tid];
  __syncthreads();
  float t = fc3_b[tid];
  for (int k = 0; k < 128; ++k) t += xrow[k] * fc3_w[k * 128 + tid];
  t = fmaxf(t, 0.f);
  float s1 = t, s2 = t * t;
#pragma unroll
  for (int m = 1; m < 64; m <<= 1) { s1 += __shfl_xor(s1, m); s2 += __shfl_xor(s2, m); }
  if ((tid & 63) == 0) { red[(tid >> 6) * 2] = s1; red[(tid >> 6) * 2 + 1] = s2; }
  __syncthreads();
  s1 = red[0] + red[2]; s2 = red[1] + red[3];
  float mean = s1 * 0.0078125f;
  float var  = s2 * 0.0078125f - mean * mean;
  float inv  = rsqrtf(var + 1e-5f);
  float v = (t - mean) * inv * ln3_g[tid] + ln3_b[tid];
  float alpha = __expf(sws[b * 32 + agent_id[b]] - stats[0]) / stats[1];
  __syncthreads();
  xrow[tid] = alpha * v;
  __syncthreads();
  float x = fc4_b[tid];
  for (int k = 0; k < 128; ++k) x += xrow[k] * fc4_w[k * 128 + tid];
  x = fmaxf(x, 0.f);
  s1 = x; s2 = x * x;
#pragma unroll
  for (int m = 1; m < 64; m <<= 1) { s1 += __shfl_xor(s1, m); s2 += __shfl_xor(s2, m); }
  if ((tid & 63) == 0) { red[4 + (tid >> 6) * 2] = s1; red[5 + (tid >> 6) * 2] = s2; }
  __syncthreads();
  s1 = red[4] + red[6]; s2 = red[5] + red[7];
  mean = s1 * 0.0078125f;
  var  = s2 * 0.0078125f - mean * mean;
  inv  = rsqrtf(var + 1e-5f);
  out[b * 128 + tid] = (x - mean) * inv * ln4_g[tid] + ln4_b[tid];
}

// ---------------------------------------------------------------------------
extern "C" void kernel_launch(void* const* d_in, const int* in_sizes, int n_in,
                              void* d_out, int out_size, void* d_ws, size_t ws_size,
                              hipStream_t stream) {
  (void)in_sizes; (void)n_in; (void)out_size; (void)ws_size;
  const float* node_obs = (const float*)d_in[0];
  const float* adj      = (const float*)d_in[1];
  const int*   agent_id = (const int*)d_in[2];
  const float* ent_emb  = (const float*)d_in[3];
  const float* lin1_w   = (const float*)d_in[4];
  const float* lin1_b   = (const float*)d_in[5];
  const float* ln1_g    = (const float*)d_in[6];
  const float* ln1_beta = (const float*)d_in[7];
  const float* linh_w   = (const float*)d_in[8];
  const float* linh_b   = (const float*)d_in[9];
  const float* lnh_g    = (const float*)d_in[10];
  const float* lnh_b    = (const float*)d_in[11];
  // d_in[12] fc2a_w used in k_prep
  const float* fc2a_b   = (const float*)d_in[13];
  const float* fc2b_w   = (const float*)d_in[14];
  const float* fc2b_b   = (const float*)d_in[15];
  const float* fc3_w    = (const float*)d_in[16];
  const float* fc3_b    = (const float*)d_in[17];
  const float* ln3_g    = (const float*)d_in[18];
  const float* ln3_b    = (const float*)d_in[19];
  const float* fc4_w    = (const float*)d_in[20];
  const float* fc4_b    = (const float*)d_in[21];
  const float* ln4_g    = (const float*)d_in[22];
  const float* ln4_b    = (const float*)d_in[23];
  float* out = (float*)d_out;
  char* ws = (char*)d_ws;

  k_prep<<<(PREP_N3 + 255) / 256, 256, 0, stream>>>(node_obs, ent_emb, lin1_w, linh_w,
                                                    (const float*)d_in[12], ws);
  k_pair<<<4096, 256, 0, stream>>>(adj, agent_id, lin1_b, ln1_g, ln1_beta,
                                   linh_b, lnh_g, lnh_b, ws);
  k_score<<<128, 256, 0, stream>>>(ws, fc2a_b, fc2b_w, fc2b_b);
  k_stats<<<1, 1024, 0, stream>>>(ws);
  k_final<<<512, 128, 0, stream>>>(ws, agent_id,
                                   fc3_w, fc3_b, ln3_g, ln3_b,
                                   fc4_w, fc4_b, ln4_g, ln4_b, out);
}